// Round 18
// baseline (166.272 us; speedup 1.0000x reference)
//
#include <hip/hip_runtime.h>

// Fused causal attention head: B=4, T=4096, D=384, K=64.
// All operands FRAGMENT-LINEAR for 32x32x16 MFMA: frag = [lane(64)][j(8)] u16 (1KB),
// index: lane&31 = m/n, lane>>5 = k-half, j = k&7; ksegs of 16 k each.
// Yk/Yq: tile(b, t32) = 4 ksegs (feat 0..63)            -> 2048 u16
// Vt:    tile(b, d>>5, key>>7) = 8 ksegs (128 keys)     -> 4096 u16
// Wka/Wqa: tile(fout>>5) x 24 ksegs (fin)               -> 12288 u16 each x2
// Wvb:     tile(d>>5)    x 24 ksegs (fin)               -> 12288 u16 x12
// Softmax: fixed-base (no max) — scores/8 ~ O(1), exp2 args small, fp32-safe.
//
// R17/R18: single knob vs R16. R12/R16's flash pipeline needs ~192+ live VGPRs
// (vf 96 + acc 48 + qf/kf/kfn 48); measured VGPR_Count=128 proves the
// (256,2) bounds pushed the allocator to a 128-reg solution that re-sank the
// V prefetch (3rd occurrence of the sink pathology) — so "prefetch is null"
// (R12) was never actually tested. (256,1) lifts the pressure; natural ~220
// still fits 2 waves/SIMD (occupancy step at 256) so 2 blocks/CU pairing is
// preserved. Decisive counter: VGPR_Count ~190-256 => pipeline held.

#define BB 4
#define TT 4096
#define DD 384

#define OWKA 0
#define OWQA 24576
#define OWVB 49152
#define OYK  196608
#define OYQ  1245184
#define OVT  2293760

#define C_EXP 0.18033688011112042f  // log2(e)/8

typedef __bf16 bf16x8 __attribute__((ext_vector_type(8)));
typedef float f32x16 __attribute__((ext_vector_type(16)));
typedef float f32x4 __attribute__((ext_vector_type(4)));
typedef unsigned short u16x4 __attribute__((ext_vector_type(4)));

__device__ __forceinline__ unsigned short f2bf(float f) {
  unsigned int u = __builtin_bit_cast(unsigned int, f);
  u += 0x7FFFu + ((u >> 16) & 1u);
  return (unsigned short)(u >> 16);
}

__device__ __forceinline__ bf16x8 ldb8(const unsigned short* p) {
  return *reinterpret_cast<const bf16x8*>(p);
}

// ---------------- 1. Weight convert -> frag-linear (Wk/Wq A-frag, Wv B-frag) --------
__global__ __launch_bounds__(256) void convert_w(
    const float* __restrict__ Wk, const float* __restrict__ Wq,
    const float* __restrict__ Wv, unsigned short* __restrict__ ws) {
  int g = blockIdx.x * 256 + threadIdx.x;    // 512 rows x 96 float4 = 49152
  int row = g / 96;
  int fin = (g - row * 96) * 4;
  const float* src;
  unsigned short* dstbase;
  int m;
  if (row < 64)       { src = Wk + row * 384;         dstbase = ws + OWKA; m = row; }
  else if (row < 128) { src = Wq + (row - 64) * 384;  dstbase = ws + OWQA; m = row - 64; }
  else                { src = Wv + (row - 128) * 384; dstbase = ws + OWVB; m = row - 128; }
  float4 f = *reinterpret_cast<const float4*>(src + fin);
  u16x4 o;
  o[0] = f2bf(f.x); o[1] = f2bf(f.y); o[2] = f2bf(f.z); o[3] = f2bf(f.w);
  unsigned short* dst = dstbase + (m >> 5) * 12288 + (fin >> 4) * 512
                        + ((((fin >> 3) & 1) << 5) + (m & 31)) * 8 + (fin & 7);
  *reinterpret_cast<u16x4*>(dst) = o;
}

// ---------------- 2. Fused K/Q/V projection (R11: chunked weight prefetch) ---------
// Block = 32 tokens (one t32 tile), 512 threads (8 waves), 512 blocks.
// X staged once in LDS frag-linear, coalesced. Waves: wid0 = Yk, wid1 = Yq,
// wid2-7 = V (2 d-tiles each). ks loop = 3 chunks x 8 ksegs: chunk c+1's 16
// weight frags issued (fence) before computing chunk c from registers.
__global__ __launch_bounds__(512) void proj_fused(
    const float* __restrict__ x, const unsigned short* __restrict__ ws_r,
    unsigned short* __restrict__ Yk, unsigned short* __restrict__ Yq,
    unsigned short* __restrict__ Vt) {
  __shared__ __align__(16) unsigned short xlds[12288];   // [kseg(24)][64][8] = 24 KB
  int tb2 = blockIdx.x;                       // 0..511 (32-token blocks)
  int b = tb2 >> 7;                           // batch
  int tt = tb2 & 127;                         // t32 index within batch
  int tid = threadIdx.x;
  {
    const float* xb = x + tb2 * 12288;
#pragma unroll
    for (int j = 0; j < 6; j++) {
      int v = tid + 512 * j;
      int r = v / 96;
      int fin = (v - r * 96) * 4;
      float4 f = *reinterpret_cast<const float4*>(xb + v * 4);
      u16x4 o;
      o[0] = f2bf(f.x); o[1] = f2bf(f.y); o[2] = f2bf(f.z); o[3] = f2bf(f.w);
      unsigned short* dst = xlds + (fin >> 4) * 512
                            + ((((fin >> 3) & 1) << 5) + r) * 8 + (fin & 7);
      *reinterpret_cast<u16x4*>(dst) = o;
    }
  }
  __syncthreads();
  int wid = tid >> 6, lane = tid & 63;
  int l31 = lane & 31, h8 = lane >> 5;
  const f32x16 fz16 = {};
  if (wid < 2) {
    const unsigned short* Wa = ws_r + (wid ? OWQA : OWKA) + lane * 8;
    unsigned short* Ysel = (wid ? Yq : Yk);
    f32x16 acc0 = fz16, acc1 = fz16;
    bf16x8 cw0[8], cw1[8], nw0[8], nw1[8];
#pragma unroll
    for (int i = 0; i < 8; i++) {
      cw0[i] = ldb8(Wa + i * 512);
      cw1[i] = ldb8(Wa + 12288 + i * 512);
    }
    asm volatile("" ::: "memory");
#pragma unroll
    for (int c = 0; c < 3; c++) {
      if (c < 2) {
#pragma unroll
        for (int i = 0; i < 8; i++) {
          nw0[i] = ldb8(Wa + (c + 1) * 4096 + i * 512);
          nw1[i] = ldb8(Wa + 12288 + (c + 1) * 4096 + i * 512);
        }
        asm volatile("" ::: "memory");
      }
#pragma unroll
      for (int i = 0; i < 8; i++) {
        bf16x8 b0 = ldb8(xlds + (c * 8 + i) * 512 + lane * 8);
        acc0 = __builtin_amdgcn_mfma_f32_32x32x16_bf16(cw0[i], b0, acc0, 0, 0, 0);
        acc1 = __builtin_amdgcn_mfma_f32_32x32x16_bf16(cw1[i], b0, acc1, 0, 0, 0);
      }
      if (c < 2) {
#pragma unroll
        for (int i = 0; i < 8; i++) { cw0[i] = nw0[i]; cw1[i] = nw1[i]; }
      }
    }
    int tile = b * 128 + tt;
    f32x16 am[2] = {acc0, acc1};
#pragma unroll
    for (int mt = 0; mt < 2; mt++)
#pragma unroll
      for (int rg = 0; rg < 4; rg++) {
        u16x4 o;
#pragma unroll
        for (int i = 0; i < 4; i++) o[i] = f2bf(am[mt][rg * 4 + i]);
        *reinterpret_cast<u16x4*>(Ysel + tile * 2048 + (mt * 2 + (rg >> 1)) * 512
                                  + (((rg & 1) << 5) + l31) * 8 + 4 * h8) = o;
      }
  } else {
    int vw = wid - 2;
    const unsigned short* Wb = ws_r + OWVB + vw * 2 * 12288 + lane * 8;
    f32x16 acc0 = fz16, acc1 = fz16;
    bf16x8 cw0[8], cw1[8], nw0[8], nw1[8];
#pragma unroll
    for (int i = 0; i < 8; i++) {
      cw0[i] = ldb8(Wb + i * 512);
      cw1[i] = ldb8(Wb + 12288 + i * 512);
    }
    asm volatile("" ::: "memory");
#pragma unroll
    for (int c = 0; c < 3; c++) {
      if (c < 2) {
#pragma unroll
        for (int i = 0; i < 8; i++) {
          nw0[i] = ldb8(Wb + (c + 1) * 4096 + i * 512);
          nw1[i] = ldb8(Wb + 12288 + (c + 1) * 4096 + i * 512);
        }
        asm volatile("" ::: "memory");
      }
#pragma unroll
      for (int i = 0; i < 8; i++) {
        bf16x8 a0 = ldb8(xlds + (c * 8 + i) * 512 + lane * 8);
        acc0 = __builtin_amdgcn_mfma_f32_32x32x16_bf16(a0, cw0[i], acc0, 0, 0, 0);
        acc1 = __builtin_amdgcn_mfma_f32_32x32x16_bf16(a0, cw1[i], acc1, 0, 0, 0);
      }
      if (c < 2) {
#pragma unroll
        for (int i = 0; i < 8; i++) { cw0[i] = nw0[i]; cw1[i] = nw1[i]; }
      }
    }
    int k128 = tt >> 2;                       // key-block within batch
    int ks0 = (tb2 & 3) * 2;                  // kseg base within 128-key tile
    f32x16 ad[2] = {acc0, acc1};
#pragma unroll
    for (int dt = 0; dt < 2; dt++) {
      int dti = vw * 2 + dt;
      unsigned short* vbase = Vt + ((b * 12 + dti) * 32 + k128) * 4096;
#pragma unroll
      for (int rg = 0; rg < 4; rg++) {
        u16x4 o;
#pragma unroll
        for (int i = 0; i < 4; i++) o[i] = f2bf(ad[dt][rg * 4 + i]);
        int kseg = ks0 + (rg >> 1);
        *reinterpret_cast<u16x4*>(vbase + kseg * 512
                                  + (((rg & 1) << 5) + l31) * 8 + 4 * h8) = o;
      }
    }
  }
}

// ---------------- 3. Flash attention: lgkm-only barrier + prefetch + nt stores -----
// R12 engine + R15 nt stores. R17/R18: __launch_bounds__(256, 1) — lift the
// 128-reg allocator squeeze so vf (96 regs) stays live across the back-edge
// and the fenced 1-iter prefetch actually holds. Natural ~220 regs still fits
// 2 waves/SIMD (step at 256) => 2 blocks/CU pairing preserved.
__global__ __launch_bounds__(256, 1) void flash_attn(
    const unsigned short* __restrict__ Yk, const unsigned short* __restrict__ Yq,
    const unsigned short* __restrict__ Vt, float* __restrict__ out) {
  __shared__ __align__(16) unsigned short pbuf[2][8192];  // [kseg(8)][lane(64)][j(8)]
  __shared__ float lred[4][32];
  int blk = blockIdx.x;
  int xcd = blk & 7;
  int b = xcd >> 1, half = xcd & 1;
  int n = blk >> 3;
  int st = (n < 32) ? (127 - 2 * n - half) : (2 * (n - 32) + half);
  int wid = threadIdx.x >> 6, lane = threadIdx.x & 63;
  int l31 = lane & 31, h8 = lane >> 5;
  const f32x16 fz16 = {};
  const unsigned short* qbase = Yq + (b * 128 + st) * 2048 + lane * 8;
  bf16x8 qf[4];
#pragma unroll
  for (int ks = 0; ks < 4; ks++) qf[ks] = ldb8(qbase + ks * 512);
  f32x16 acc[3];
  acc[0] = fz16; acc[1] = fz16; acc[2] = fz16;
  float psum = 0.f;
  int n128 = (st >> 2) + 1;
  int qrow = st * 32 + l31;
  const unsigned short* kbase = Yk + (b * 128 + wid) * 2048 + lane * 8;
  const unsigned short* vbase = Vt + ((b * 12 + wid * 3) * 32) * 4096 + lane * 8;
  // prologue: K(0), V(0) in flight
  bf16x8 kf[4];
#pragma unroll
  for (int ks = 0; ks < 4; ks++) kf[ks] = ldb8(kbase + ks * 512);
  bf16x8 vf0[8], vf1[8], vf2[8];
#pragma unroll
  for (int g = 0; g < 8; g++) vf0[g] = ldb8(vbase + g * 512);
#pragma unroll
  for (int g = 0; g < 8; g++) vf1[g] = ldb8(vbase + 32 * 4096 + g * 512);
#pragma unroll
  for (int g = 0; g < 8; g++) vf2[g] = ldb8(vbase + 64 * 4096 + g * 512);
  asm volatile("" ::: "memory");
#pragma unroll 1
  for (int kb = 0; kb < n128; kb++) {
    f32x16 sacc = fz16;
#pragma unroll
    for (int ks = 0; ks < 4; ks++)
      sacc = __builtin_amdgcn_mfma_f32_32x32x16_bf16(kf[ks], qf[ks], sacc, 0, 0, 0);
    // prefetch K(kb+1): lands during exp/barrier/PV
    int kn = (kb + 1 < n128) ? kb + 1 : kb;
    const unsigned short* ktn = kbase + kn * 8192;
    bf16x8 kfn[4];
#pragma unroll
    for (int ks = 0; ks < 4; ks++) kfn[ks] = ldb8(ktn + ks * 512);
    asm volatile("" ::: "memory");
    int kg0 = kb * 128 + wid * 32 + 4 * h8;
    unsigned short* pw = pbuf[kb & 1];
#pragma unroll
    for (int rg = 0; rg < 4; rg++) {
      u16x4 o;
#pragma unroll
      for (int i = 0; i < 4; i++) {
        int key = kg0 + rg * 8 + i;
        float pv = (key > qrow) ? 0.f : exp2f(sacc[rg * 4 + i] * C_EXP);
        psum += pv;
        o[i] = f2bf(pv);
      }
      int g = wid * 2 + (rg >> 1);
      *reinterpret_cast<u16x4*>(pw + g * 512 + ((rg & 1) * 32 + l31) * 8 + 4 * h8) = o;
    }
    // lgkm-only barrier: commits P writes (and drains last iter's P reads) but
    // leaves the prefetched global loads in flight — no vmcnt(0) drain.
    asm volatile("s_waitcnt lgkmcnt(0)" ::: "memory");
    __builtin_amdgcn_s_barrier();
    asm volatile("" ::: "memory");
    bf16x8 pf[8];
#pragma unroll
    for (int g = 0; g < 8; g++) pf[g] = ldb8(pw + g * 512 + lane * 8);
#pragma unroll
    for (int g = 0; g < 8; g++) {
      acc[0] = __builtin_amdgcn_mfma_f32_32x32x16_bf16(vf0[g], pf[g], acc[0], 0, 0, 0);
      acc[1] = __builtin_amdgcn_mfma_f32_32x32x16_bf16(vf1[g], pf[g], acc[1], 0, 0, 0);
      acc[2] = __builtin_amdgcn_mfma_f32_32x32x16_bf16(vf2[g], pf[g], acc[2], 0, 0, 0);
    }
    // prefetch V(kb+1): lands during next QK/exp/barrier
    const unsigned short* vtn = vbase + kn * 4096;
#pragma unroll
    for (int g = 0; g < 8; g++) vf0[g] = ldb8(vtn + g * 512);
#pragma unroll
    for (int g = 0; g < 8; g++) vf1[g] = ldb8(vtn + 32 * 4096 + g * 512);
#pragma unroll
    for (int g = 0; g < 8; g++) vf2[g] = ldb8(vtn + 64 * 4096 + g * 512);
    asm volatile("" ::: "memory");
#pragma unroll
    for (int ks = 0; ks < 4; ks++) kf[ks] = kfn[ks];
  }
  psum += __shfl_xor(psum, 32);
  if (h8 == 0) lred[wid][l31] = psum;
  __syncthreads();
  float lt = lred[0][l31] + lred[1][l31] + lred[2][l31] + lred[3][l31];
  float inv = 1.0f / lt;
  float* ob = out + (b * TT + st * 32 + l31) * DD + wid * 96;
#pragma unroll
  for (int dt = 0; dt < 3; dt++)
#pragma unroll
    for (int rg = 0; rg < 4; rg++) {
      f32x4 o4;
      o4[0] = acc[dt][rg * 4 + 0] * inv; o4[1] = acc[dt][rg * 4 + 1] * inv;
      o4[2] = acc[dt][rg * 4 + 2] * inv; o4[3] = acc[dt][rg * 4 + 3] * inv;
      __builtin_nontemporal_store(
          o4, reinterpret_cast<f32x4*>(ob + dt * 32 + rg * 8 + h8 * 4));
    }
}

extern "C" void kernel_launch(void* const* d_in, const int* in_sizes, int n_in,
                              void* d_out, int out_size, void* d_ws, size_t ws_size,
                              hipStream_t stream) {
  const float* x  = (const float*)d_in[0];
  const float* Wk = (const float*)d_in[1];
  const float* Wq = (const float*)d_in[2];
  const float* Wv = (const float*)d_in[3];
  unsigned short* ws = (unsigned short*)d_ws;
  unsigned short* Yk = ws + OYK;
  unsigned short* Yq = ws + OYQ;
  unsigned short* Vt = ws + OVT;

  convert_w<<<192, 256, 0, stream>>>(Wk, Wq, Wv, ws);
  proj_fused<<<512, 512, 0, stream>>>(x, ws, Yk, Yq, Vt);
  flash_attn<<<512, 256, 0, stream>>>(Yk, Yq, Vt, (float*)d_out);
}